// Round 12
// baseline (367.104 us; speedup 1.0000x reference)
//
#include <hip/hip_runtime.h>
#include <hip/hip_bf16.h>

typedef __bf16 bf16x8 __attribute__((ext_vector_type(8)));
typedef float f32x4 __attribute__((ext_vector_type(4)));

using bf = __hip_bfloat16;

constexpr int cB = 16, cH = 96, cW = 96, cC = 192;
constexpr int cT = cH * cW;       // 9216
constexpr int cM = cB * cT;       // 147456
constexpr int CH = 48;            // wkv chunk length
constexpr int NS = cT / CH;       // 192 chunks
constexpr int NSTR = cM / 16;     // 9216 16-row stripes
constexpr float Tinv = 1.0f / 9216.0f;

__device__ __forceinline__ float bflo(unsigned u) { return __uint_as_float(u << 16); }
__device__ __forceinline__ float bfhi(unsigned u) { return __uint_as_float(u & 0xffff0000u); }

// ---------------------------------------------------------------------------
// Pre-convert weights f32 -> bf16, concatenated rows: [Wk;Wv;Wr;Wo] (768x192)
// ---------------------------------------------------------------------------
__global__ __launch_bounds__(256) void convw_k(
    const float* __restrict__ Wk, const float* __restrict__ Wv,
    const float* __restrict__ Wr, const float* __restrict__ Wo,
    bf* __restrict__ out)
{
    int i = (blockIdx.x * 256 + threadIdx.x) * 8;
    int mat = i / 36864, off = i % 36864;
    const float* s = mat == 0 ? Wk : (mat == 1 ? Wv : (mat == 2 ? Wr : Wo));
    const float4* sp = reinterpret_cast<const float4*>(s + off);
    float4 a0 = sp[0], a1 = sp[1];
    bf16x8 pk;
    pk[0]=(__bf16)a0.x; pk[1]=(__bf16)a0.y; pk[2]=(__bf16)a0.z; pk[3]=(__bf16)a0.w;
    pk[4]=(__bf16)a1.x; pk[5]=(__bf16)a1.y; pk[6]=(__bf16)a1.z; pk[7]=(__bf16)a1.w;
    *reinterpret_cast<bf16x8*>(reinterpret_cast<__bf16*>(out) + i) = pk;
}

// ---------------------------------------------------------------------------
// LDS-free, barrier-free GEMM. Block = 768 thr = 12 waves; wave wn owns 16
// output channels (12x16 = 192). All waves work the SAME 16-row stripe per
// iteration, so their identical A-fragment loads hit L1/L2.
// A-fragment = direct coalesced global int4 load (lane: row=lane&15,
// k=(lane>>4)*8) — exactly the MFMA A layout, no staging needed.
// B fragments live in registers: 6 frags/mat, ALL mats at once (MODE 0: 18
// frags = 72 VGPR) -> the 3 GEMMs fuse, x is read ONCE with the 2D shift
// applied in the load (source channel group selects shifted row).
// Stores: R7-proven scalar pattern (per instr: 4 rows x 32B contiguous).
// MODE 0: A = x (f32, fused shift); outputs k/v/sigmoid(r) bf16 [m][c].
// MODE 1: A = z (bf16); 1 mat (Wo) -> out f32 [m][c].
// ---------------------------------------------------------------------------
template <int MODE>
__global__ __launch_bounds__(768) void gemm_f(
    const void* __restrict__ Ap, const bf* __restrict__ Wb,
    void* __restrict__ O0, void* __restrict__ O1, void* __restrict__ O2)
{
    constexpr int NMAT = (MODE == 0) ? 3 : 1;
    const int tid = threadIdx.x;
    const int lane = tid & 63, wn = tid >> 6;   // 12 waves
    const int lr = lane & 15, lq = lane >> 4;
    const int ch0 = wn * 16;

    // ---- B fragments -> registers, once (weights L2-resident) ----
    bf16x8 bw[NMAT][6];
#pragma unroll
    for (int mat = 0; mat < NMAT; ++mat)
#pragma unroll
        for (int kk = 0; kk < 6; ++kk)
            bw[mat][kk] = *reinterpret_cast<const bf16x8*>(
                Wb + (size_t)mat * 192 * cC + (size_t)(ch0 + lr) * cC + kk * 32 + lq * 8);

    for (int s = blockIdx.x; s < NSTR; s += gridDim.x) {
        const int m0 = s * 16;
        const int m = m0 + lr;                  // this lane's A row
        bf16x8 af[6];
        if constexpr (MODE == 0) {
            const float* x = (const float*)Ap;
            int bidx = m / cT, t = m % cT, h = t / cW, w = t % cW;
            const float* xb = x + (size_t)bidx * cT * cC;
            const float* p0 = xb + ((size_t)h * cW + (w - 1)) * cC;       // grp0: from w-1
            const float* p1 = xb + ((size_t)h * cW + (w + 1)) * cC;       // grp1: from w+1
            const float* p2 = xb + ((size_t)(h - 1) * cW + w) * cC;       // grp2: from h-1
            const float* p3 = xb + ((size_t)(h + 1) * cW + w) * cC;       // grp3: from h+1
            bool v0 = (w > 0), v1 = (w < cW - 1), v2 = (h > 0), v3 = (h < cH - 1);
#pragma unroll
            for (int kk = 0; kk < 6; ++kk) {
                int c = kk * 32 + lq * 8;       // source channel == dest channel
                int grp = c / 48;
                const float* pp = grp == 0 ? p0 : (grp == 1 ? p1 : (grp == 2 ? p2 : p3));
                bool vv = grp == 0 ? v0 : (grp == 1 ? v1 : (grp == 2 ? v2 : v3));
                float4 a0{0,0,0,0}, a1{0,0,0,0};
                if (vv) {
                    const float4* sp = reinterpret_cast<const float4*>(pp + c);
                    a0 = sp[0]; a1 = sp[1];
                }
                bf16x8 pk;
                pk[0]=(__bf16)a0.x; pk[1]=(__bf16)a0.y; pk[2]=(__bf16)a0.z; pk[3]=(__bf16)a0.w;
                pk[4]=(__bf16)a1.x; pk[5]=(__bf16)a1.y; pk[6]=(__bf16)a1.z; pk[7]=(__bf16)a1.w;
                af[kk] = pk;
            }
        } else {
            const bf* Az = (const bf*)Ap;
#pragma unroll
            for (int kk = 0; kk < 6; ++kk)
                af[kk] = *reinterpret_cast<const bf16x8*>(
                    Az + (size_t)m * cC + kk * 32 + lq * 8);
        }

        f32x4 acc[NMAT] = {};
#pragma unroll
        for (int kk = 0; kk < 6; ++kk)
#pragma unroll
            for (int mat = 0; mat < NMAT; ++mat)
                acc[mat] = __builtin_amdgcn_mfma_f32_16x16x32_bf16(
                    af[kk], bw[mat][kk], acc[mat], 0, 0, 0);

        if constexpr (MODE == 0) {
#pragma unroll
            for (int mat = 0; mat < 3; ++mat) {
                f32x4 a = acc[mat];
                if (mat == 2) {
#pragma unroll
                    for (int j = 0; j < 4; ++j) a[j] = 1.0f / (1.0f + __expf(-a[j]));
                }
                bf* Os = (bf*)(mat == 0 ? O0 : (mat == 1 ? O1 : O2));
#pragma unroll
                for (int j = 0; j < 4; ++j)
                    Os[(size_t)(m0 + lq * 4 + j) * cC + ch0 + lr] = __float2bfloat16(a[j]);
            }
        } else {
            float* Os = (float*)O0;
#pragma unroll
            for (int j = 0; j < 4; ++j)
                Os[(size_t)(m0 + lq * 4 + j) * cC + ch0 + lr] = acc[0][j];
        }
    }
}

// ---------------------------------------------------------------------------
// WKV chunked scan over [m][c] bf16, 2 channels/thread, CH=48 (NS=192 chunks),
// per-step software prefetch. State: true numerator = p*e^o, denom = q*e^o.
// ---------------------------------------------------------------------------
__global__ __launch_bounds__(192) void wkv_pass1(
    const bf* __restrict__ k, const bf* __restrict__ v,
    const float* __restrict__ sd,
    float* __restrict__ stP, float* __restrict__ stQ, float* __restrict__ stO)
{
    const int c2 = threadIdx.x % 96, sub = threadIdx.x / 96;
    const int b = blockIdx.y, ch = blockIdx.x * 2 + sub;
    const int c0 = c2 * 2;
    const float w0 = sd[c0] * Tinv, w1 = sd[c0 + 1] * Tinv;
    size_t base = ((size_t)b * cT + (size_t)ch * CH) * cC + c0;
    float p0 = 0.f, q0 = 0.f, o0 = -1e38f;
    float p1 = 0.f, q1 = 0.f, o1 = -1e38f;
    unsigned kwc = *reinterpret_cast<const unsigned*>(k + base);
    unsigned vwc = *reinterpret_cast<const unsigned*>(v + base);
    for (int s = 0; s < CH; ++s) {
        unsigned kwn = 0, vwn = 0;
        if (s + 1 < CH) {
            kwn = *reinterpret_cast<const unsigned*>(k + base + (size_t)(s + 1) * cC);
            vwn = *reinterpret_cast<const unsigned*>(v + base + (size_t)(s + 1) * cC);
        }
        float kt0 = bflo(kwc), kt1 = bfhi(kwc);
        float vt0 = bflo(vwc), vt1 = bfhi(vwc);
        float no0 = fmaxf(w0 + o0, kt0);
        float A0 = __expf(w0 + o0 - no0), B0 = __expf(kt0 - no0);
        p0 = A0 * p0 + B0 * vt0; q0 = A0 * q0 + B0; o0 = no0;
        float no1 = fmaxf(w1 + o1, kt1);
        float A1 = __expf(w1 + o1 - no1), B1 = __expf(kt1 - no1);
        p1 = A1 * p1 + B1 * vt1; q1 = A1 * q1 + B1; o1 = no1;
        kwc = kwn; vwc = vwn;
    }
    size_t si = ((size_t)b * NS + ch) * cC + c0;
    *reinterpret_cast<float2*>(stP + si) = make_float2(p0, p1);
    *reinterpret_cast<float2*>(stQ + si) = make_float2(q0, q1);
    *reinterpret_cast<float2*>(stO + si) = make_float2(o0, o1);
}

// In-place exclusive prefix over chunk states.
__global__ __launch_bounds__(192) void wkv_pass2(
    float* __restrict__ stP, float* __restrict__ stQ, float* __restrict__ stO,
    const float* __restrict__ sd)
{
    const int c = threadIdx.x, b = blockIdx.x;
    const float w = sd[c] * Tinv;
    const float Lw = w * (float)CH;
    float p = 0.f, q = 0.f, o = -1e38f;
    size_t si = (size_t)b * NS * cC + c;
    float sp = stP[si], sq = stQ[si], so = stO[si];
    for (int ch = 0; ch < NS; ++ch) {
        float np_ = 0.f, nq_ = 0.f, no_ = -1e38f;
        if (ch + 1 < NS) {
            size_t sj = si + (size_t)(ch + 1) * cC;
            np_ = stP[sj]; nq_ = stQ[sj]; no_ = stO[sj];
        }
        size_t sc = si + (size_t)ch * cC;
        stP[sc] = p; stQ[sc] = q; stO[sc] = o;
        float po = o + Lw;
        float m = fmaxf(po, so);
        float e1 = __expf(po - m), e2 = __expf(so - m);
        p = e1 * p + e2 * sp;
        q = e1 * q + e2 * sq;
        o = m;
        sp = np_; sq = nq_; so = no_;
    }
}

__global__ __launch_bounds__(192) void wkv_pass3(
    const bf* __restrict__ k, const bf* __restrict__ v, const bf* __restrict__ sr,
    const float* __restrict__ sd, const float* __restrict__ sf,
    const float* __restrict__ iP, const float* __restrict__ iQ,
    const float* __restrict__ iO, bf* __restrict__ z)
{
    const int c2 = threadIdx.x % 96, sub = threadIdx.x / 96;
    const int b = blockIdx.y, ch = blockIdx.x * 2 + sub;
    const int c0 = c2 * 2;
    const float w0 = sd[c0] * Tinv, w1 = sd[c0 + 1] * Tinv;
    const float u0 = sf[c0] * Tinv, u1 = sf[c0 + 1] * Tinv;
    size_t si = ((size_t)b * NS + ch) * cC + c0;
    float2 pp = *reinterpret_cast<const float2*>(iP + si);
    float2 qq = *reinterpret_cast<const float2*>(iQ + si);
    float2 oo = *reinterpret_cast<const float2*>(iO + si);
    float p0 = pp.x, q0 = qq.x, o0 = oo.x;
    float p1 = pp.y, q1 = qq.y, o1 = oo.y;
    size_t base = ((size_t)b * cT + (size_t)ch * CH) * cC + c0;
    unsigned kwc = *reinterpret_cast<const unsigned*>(k + base);
    unsigned vwc = *reinterpret_cast<const unsigned*>(v + base);
    unsigned rwc = *reinterpret_cast<const unsigned*>(sr + base);
    for (int s = 0; s < CH; ++s) {
        unsigned kwn = 0, vwn = 0, rwn = 0;
        if (s + 1 < CH) {
            size_t nx = base + (size_t)(s + 1) * cC;
            kwn = *reinterpret_cast<const unsigned*>(k + nx);
            vwn = *reinterpret_cast<const unsigned*>(v + nx);
            rwn = *reinterpret_cast<const unsigned*>(sr + nx);
        }
        float kt0 = bflo(kwc), kt1 = bfhi(kwc);
        float vt0 = bflo(vwc), vt1 = bfhi(vwc);
        float rt0 = bflo(rwc), rt1 = bfhi(rwc);

        float no0 = fmaxf(o0, u0 + kt0);
        float Ae0 = __expf(o0 - no0), Be0 = __expf(u0 + kt0 - no0);
        float y0 = (Ae0 * p0 + Be0 * vt0) / (Ae0 * q0 + Be0);
        float no1 = fmaxf(o1, u1 + kt1);
        float Ae1 = __expf(o1 - no1), Be1 = __expf(u1 + kt1 - no1);
        float y1 = (Ae1 * p1 + Be1 * vt1) / (Ae1 * q1 + Be1);

        bf z0 = __float2bfloat16(rt0 * y0);
        bf z1 = __float2bfloat16(rt1 * y1);
        unsigned zp = (unsigned)*reinterpret_cast<unsigned short*>(&z0)
                    | ((unsigned)*reinterpret_cast<unsigned short*>(&z1) << 16);
        *reinterpret_cast<unsigned*>(z + base + (size_t)s * cC) = zp;

        float m0 = fmaxf(w0 + o0, kt0);
        float A0 = __expf(w0 + o0 - m0), B0 = __expf(kt0 - m0);
        p0 = A0 * p0 + B0 * vt0; q0 = A0 * q0 + B0; o0 = m0;
        float m1 = fmaxf(w1 + o1, kt1);
        float A1 = __expf(w1 + o1 - m1), B1 = __expf(kt1 - m1);
        p1 = A1 * p1 + B1 * vt1; q1 = A1 * q1 + B1; o1 = m1;
        kwc = kwn; vwc = vwn; rwc = rwn;
    }
}

extern "C" void kernel_launch(void* const* d_in, const int* in_sizes, int n_in,
                              void* d_out, int out_size, void* d_ws, size_t ws_size,
                              hipStream_t stream)
{
    const float* x  = (const float*)d_in[0];
    const float* Wk = (const float*)d_in[1];
    const float* Wv = (const float*)d_in[2];
    const float* Wr = (const float*)d_in[3];
    const float* Wo = (const float*)d_in[4];
    const float* sd = (const float*)d_in[5];
    const float* sf = (const float*)d_in[6];
    float* out = (float*)d_out;

    const size_t nEl = (size_t)cM * cC;          // 28,311,552 elements
    // d_out (f32, 113.2MB) holds k and sr (bf16, 2x56.6MB) until the final
    // GEMM fully overwrites it with out f32.
    bf* kbuf  = (bf*)d_out;
    bf* srbuf = (bf*)d_out + nEl;
    char* ws = (char*)d_ws;
    bf* vbuf = (bf*)ws;                           // 56.6MB
    bf* zbuf = (bf*)(ws + 2 * nEl);               // 56.6MB
    const size_t stN = (size_t)cB * NS * cC;      // 589,824 floats each
    float* stP = (float*)(ws + 4 * nEl);          // 3 x 2.36MB
    float* stQ = stP + stN;
    float* stO = stQ + stN;
    bf* wbf = (bf*)(stO + stN);                   // [Wk;Wv;Wr;Wo] bf16, 768x192

    convw_k<<<dim3(72), dim3(256), 0, stream>>>(Wk, Wv, Wr, Wo, wbf);
    gemm_f<0><<<dim3(256), dim3(768), 0, stream>>>(x, wbf, kbuf, vbuf, srbuf);
    wkv_pass1<<<dim3(NS / 2, cB), dim3(192), 0, stream>>>(kbuf, vbuf, sd, stP, stQ, stO);
    wkv_pass2<<<dim3(cB), dim3(192), 0, stream>>>(stP, stQ, stO, sd);
    wkv_pass3<<<dim3(NS / 2, cB), dim3(192), 0, stream>>>(
        kbuf, vbuf, srbuf, sd, sf, stP, stQ, stO, zbuf);
    gemm_f<1><<<dim3(256), dim3(768), 0, stream>>>(
        zbuf, wbf + (size_t)576 * cC, out, nullptr, nullptr);
}

// Round 13
// 272.717 us; speedup vs baseline: 1.3461x; 1.3461x over previous
//
#include <hip/hip_runtime.h>
#include <hip/hip_bf16.h>

typedef __bf16 bf16x8 __attribute__((ext_vector_type(8)));
typedef float f32x4 __attribute__((ext_vector_type(4)));

using bf = __hip_bfloat16;

constexpr int cB = 16, cH = 96, cW = 96, cC = 192;
constexpr int cT = cH * cW;       // 9216
constexpr int cM = cB * cT;       // 147456
constexpr int CH = 48;            // wkv chunk length
constexpr int NS = cT / CH;       // 192 chunks
constexpr float Tinv = 1.0f / 9216.0f;

__device__ __forceinline__ int swz(int row, int bytecol) {
    return row * 384 + (bytecol ^ ((row & 7) << 4));
}
__device__ __forceinline__ float bflo(unsigned u) { return __uint_as_float(u << 16); }
__device__ __forceinline__ float bfhi(unsigned u) { return __uint_as_float(u & 0xffff0000u); }

// ---------------------------------------------------------------------------
// Pre-convert weights f32 -> bf16, concatenated rows: [Wk;Wv;Wr;Wo] (768x192)
// ---------------------------------------------------------------------------
__global__ __launch_bounds__(256) void convw_k(
    const float* __restrict__ Wk, const float* __restrict__ Wv,
    const float* __restrict__ Wr, const float* __restrict__ Wo,
    bf* __restrict__ out)
{
    int i = (blockIdx.x * 256 + threadIdx.x) * 8;
    int mat = i / 36864, off = i % 36864;
    const float* s = mat == 0 ? Wk : (mat == 1 ? Wv : (mat == 2 ? Wr : Wo));
    const float4* sp = reinterpret_cast<const float4*>(s + off);
    float4 a0 = sp[0], a1 = sp[1];
    bf16x8 pk;
    pk[0]=(__bf16)a0.x; pk[1]=(__bf16)a0.y; pk[2]=(__bf16)a0.z; pk[3]=(__bf16)a0.w;
    pk[4]=(__bf16)a1.x; pk[5]=(__bf16)a1.y; pk[6]=(__bf16)a1.z; pk[7]=(__bf16)a1.w;
    *reinterpret_cast<bf16x8*>(reinterpret_cast<__bf16*>(out) + i) = pk;
}

// ---------------------------------------------------------------------------
// GEMM out[m,n] = sum_k A[m,k]*W[n,k].  BM=128, 512 threads (8 waves, 4m x 2n).
// MODE 0 (R7-proven): A = x(f32)+2D shift staged once in LDS; loop over 6
//   96-row B-tiles double-buffered -> k / v / sigmoid(r) bf16 [m][c].
// MODE 1 (full-row fix): A = z staged once; FULL Wo (192 rows) staged once;
//   ONE barrier; accumulate both n-halves; store complete f32 rows in a
//   single epilogue window (kills partial-dirty-line write amplification).
// ---------------------------------------------------------------------------
template <int MODE>
__global__ __launch_bounds__(512) void gemm_k(
    const void* __restrict__ Ap, const bf* __restrict__ Wb,
    void* __restrict__ O0, void* __restrict__ O1, void* __restrict__ O2)
{
    __shared__ char lds[128 * 384 + 2 * 96 * 384];
    char* Ab = &lds[0];
    const int tid = threadIdx.x;
    const int m0 = blockIdx.x * 128;

    // ---- stage A: 128 rows x 192 cols, bf16 swizzled ----
    if constexpr (MODE == 0) {
        const float* Af = (const float*)Ap;
        for (int i = tid; i < 128 * 24; i += 512) {
            int r = i / 24, kb = i % 24;
            int gm = m0 + r;
            int b = gm / cT, t = gm % cT;
            int h = t / cW, w = t % cW;
            int grp = kb / 6;                      // 48-channel shift group
            int hs = h + (grp == 2 ? -1 : (grp == 3 ? 1 : 0));
            int ws2 = w + (grp == 0 ? -1 : (grp == 1 ? 1 : 0));
            float4 a0{0,0,0,0}, a1{0,0,0,0};
            if (hs >= 0 && hs < cH && ws2 >= 0 && ws2 < cW) {
                const float4* src = reinterpret_cast<const float4*>(
                    Af + ((size_t)b * cT + (size_t)hs * cW + ws2) * cC + kb * 8);
                a0 = src[0]; a1 = src[1];
            }
            bf16x8 pk;
            pk[0]=(__bf16)a0.x; pk[1]=(__bf16)a0.y; pk[2]=(__bf16)a0.z; pk[3]=(__bf16)a0.w;
            pk[4]=(__bf16)a1.x; pk[5]=(__bf16)a1.y; pk[6]=(__bf16)a1.z; pk[7]=(__bf16)a1.w;
            *reinterpret_cast<bf16x8*>(Ab + swz(r, kb * 16)) = pk;
        }
    } else {
        const bf* Az = (const bf*)Ap;
        for (int i = tid; i < 128 * 24; i += 512) {
            int r = i / 24, kb = i % 24;
            int4 val = *reinterpret_cast<const int4*>(
                Az + ((size_t)(m0 + r)) * cC + kb * 8);
            *reinterpret_cast<int4*>(Ab + swz(r, kb * 16)) = val;
        }
    }

    const int lane = tid & 63, wid = tid >> 6;
    const int wm = wid >> 1, wn = wid & 1;   // 4x2 waves: 32 rows x 48 cols each
    const int lr = lane & 15, lq = lane >> 4;

    if constexpr (MODE == 0) {
        // ---- stage B tile 0 ----
        {
            char* b0 = &lds[0] + 128 * 384;
            for (int i = tid; i < 96 * 24; i += 512) {
                int r = i / 24, kb = i % 24;
                int4 val = *reinterpret_cast<const int4*>(Wb + (size_t)r * cC + kb * 8);
                *reinterpret_cast<int4*>(b0 + swz(r, kb * 16)) = val;
            }
        }
        __syncthreads();

        for (int tI = 0; tI < 6; ++tI) {
            char* cur = &lds[0] + 128 * 384 + (tI & 1) * (96 * 384);
            if (tI + 1 < 6) {                    // prefetch next B tile
                char* nxt = &lds[0] + 128 * 384 + ((tI + 1) & 1) * (96 * 384);
                const bf* Wt = Wb + (size_t)(tI + 1) * 96 * cC;
                for (int i = tid; i < 96 * 24; i += 512) {
                    int r = i / 24, kb = i % 24;
                    int4 val = *reinterpret_cast<const int4*>(Wt + (size_t)r * cC + kb * 8);
                    *reinterpret_cast<int4*>(nxt + swz(r, kb * 16)) = val;
                }
            }
            f32x4 acc[2][3] = {};
#pragma unroll
            for (int kk = 0; kk < 6; ++kk) {
                const int bc = kk * 64 + lq * 16;
                bf16x8 af[2], bfr[3];
#pragma unroll
                for (int mt = 0; mt < 2; ++mt)
                    af[mt] = *reinterpret_cast<const bf16x8*>(Ab + swz(wm * 32 + mt * 16 + lr, bc));
#pragma unroll
                for (int nt = 0; nt < 3; ++nt)
                    bfr[nt] = *reinterpret_cast<const bf16x8*>(cur + swz(wn * 48 + nt * 16 + lr, bc));
#pragma unroll
                for (int mt = 0; mt < 2; ++mt)
#pragma unroll
                    for (int nt = 0; nt < 3; ++nt)
                        acc[mt][nt] = __builtin_amdgcn_mfma_f32_16x16x32_bf16(
                            af[mt], bfr[nt], acc[mt][nt], 0, 0, 0);
            }
            int mat = tI >> 1, nc0 = (tI & 1) * 96;
            bf* Os = (bf*)(mat == 0 ? O0 : (mat == 1 ? O1 : O2));
#pragma unroll
            for (int mt = 0; mt < 2; ++mt)
#pragma unroll
                for (int nt = 0; nt < 3; ++nt)
#pragma unroll
                    for (int j = 0; j < 4; ++j) {
                        int row = m0 + wm * 32 + mt * 16 + lq * 4 + j;
                        int col = nc0 + wn * 48 + nt * 16 + lr;
                        float v = acc[mt][nt][j];
                        if (mat == 2) v = 1.0f / (1.0f + __expf(-v));
                        Os[(size_t)row * cC + col] = __float2bfloat16(v);
                    }
            __syncthreads();
        }
    } else {
        // ---- stage FULL B (192 rows, 72KB) ----
        {
            char* b0 = &lds[0] + 128 * 384;
            for (int i = tid; i < 192 * 24; i += 512) {
                int r = i / 24, kb = i % 24;
                int4 val = *reinterpret_cast<const int4*>(Wb + (size_t)r * cC + kb * 8);
                *reinterpret_cast<int4*>(b0 + swz(r, kb * 16)) = val;
            }
        }
        __syncthreads();     // the ONLY barrier

        char* Bb = &lds[0] + 128 * 384;
        f32x4 acc[2][2][3] = {};   // [half][mt][nt]
#pragma unroll
        for (int kk = 0; kk < 6; ++kk) {
            const int bc = kk * 64 + lq * 16;
            bf16x8 af[2];
#pragma unroll
            for (int mt = 0; mt < 2; ++mt)
                af[mt] = *reinterpret_cast<const bf16x8*>(Ab + swz(wm * 32 + mt * 16 + lr, bc));
#pragma unroll
            for (int half = 0; half < 2; ++half)
#pragma unroll
                for (int nt = 0; nt < 3; ++nt) {
                    bf16x8 bfr = *reinterpret_cast<const bf16x8*>(
                        Bb + swz(half * 96 + wn * 48 + nt * 16 + lr, bc));
#pragma unroll
                    for (int mt = 0; mt < 2; ++mt)
                        acc[half][mt][nt] = __builtin_amdgcn_mfma_f32_16x16x32_bf16(
                            af[mt], bfr, acc[half][mt][nt], 0, 0, 0);
                }
        }
        // ---- full-row epilogue: entire 768B f32 row within one window ----
        float* Os = (float*)O0;
#pragma unroll
        for (int mt = 0; mt < 2; ++mt)
#pragma unroll
            for (int j = 0; j < 4; ++j) {
                int row = m0 + wm * 32 + mt * 16 + lq * 4 + j;
#pragma unroll
                for (int half = 0; half < 2; ++half)
#pragma unroll
                    for (int nt = 0; nt < 3; ++nt) {
                        int col = half * 96 + wn * 48 + nt * 16 + lr;
                        Os[(size_t)row * cC + col] = acc[half][mt][nt][j];
                    }
            }
    }
}

// ---------------------------------------------------------------------------
// WKV chunked scan over [m][c] bf16, 2 channels/thread, CH=48 (NS=192 chunks),
// per-step software prefetch. State: true numerator = p*e^o, denom = q*e^o.
// ---------------------------------------------------------------------------
__global__ __launch_bounds__(192) void wkv_pass1(
    const bf* __restrict__ k, const bf* __restrict__ v,
    const float* __restrict__ sd,
    float* __restrict__ stP, float* __restrict__ stQ, float* __restrict__ stO)
{
    const int c2 = threadIdx.x % 96, sub = threadIdx.x / 96;
    const int b = blockIdx.y, ch = blockIdx.x * 2 + sub;
    const int c0 = c2 * 2;
    const float w0 = sd[c0] * Tinv, w1 = sd[c0 + 1] * Tinv;
    size_t base = ((size_t)b * cT + (size_t)ch * CH) * cC + c0;
    float p0 = 0.f, q0 = 0.f, o0 = -1e38f;
    float p1 = 0.f, q1 = 0.f, o1 = -1e38f;
    unsigned kwc = *reinterpret_cast<const unsigned*>(k + base);
    unsigned vwc = *reinterpret_cast<const unsigned*>(v + base);
    for (int s = 0; s < CH; ++s) {
        unsigned kwn = 0, vwn = 0;
        if (s + 1 < CH) {
            kwn = *reinterpret_cast<const unsigned*>(k + base + (size_t)(s + 1) * cC);
            vwn = *reinterpret_cast<const unsigned*>(v + base + (size_t)(s + 1) * cC);
        }
        float kt0 = bflo(kwc), kt1 = bfhi(kwc);
        float vt0 = bflo(vwc), vt1 = bfhi(vwc);
        float no0 = fmaxf(w0 + o0, kt0);
        float A0 = __expf(w0 + o0 - no0), B0 = __expf(kt0 - no0);
        p0 = A0 * p0 + B0 * vt0; q0 = A0 * q0 + B0; o0 = no0;
        float no1 = fmaxf(w1 + o1, kt1);
        float A1 = __expf(w1 + o1 - no1), B1 = __expf(kt1 - no1);
        p1 = A1 * p1 + B1 * vt1; q1 = A1 * q1 + B1; o1 = no1;
        kwc = kwn; vwc = vwn;
    }
    size_t si = ((size_t)b * NS + ch) * cC + c0;
    *reinterpret_cast<float2*>(stP + si) = make_float2(p0, p1);
    *reinterpret_cast<float2*>(stQ + si) = make_float2(q0, q1);
    *reinterpret_cast<float2*>(stO + si) = make_float2(o0, o1);
}

// In-place exclusive prefix over chunk states.
__global__ __launch_bounds__(192) void wkv_pass2(
    float* __restrict__ stP, float* __restrict__ stQ, float* __restrict__ stO,
    const float* __restrict__ sd)
{
    const int c = threadIdx.x, b = blockIdx.x;
    const float w = sd[c] * Tinv;
    const float Lw = w * (float)CH;
    float p = 0.f, q = 0.f, o = -1e38f;
    size_t si = (size_t)b * NS * cC + c;
    float sp = stP[si], sq = stQ[si], so = stO[si];
    for (int ch = 0; ch < NS; ++ch) {
        float np_ = 0.f, nq_ = 0.f, no_ = -1e38f;
        if (ch + 1 < NS) {
            size_t sj = si + (size_t)(ch + 1) * cC;
            np_ = stP[sj]; nq_ = stQ[sj]; no_ = stO[sj];
        }
        size_t sc = si + (size_t)ch * cC;
        stP[sc] = p; stQ[sc] = q; stO[sc] = o;
        float po = o + Lw;
        float m = fmaxf(po, so);
        float e1 = __expf(po - m), e2 = __expf(so - m);
        p = e1 * p + e2 * sp;
        q = e1 * q + e2 * sq;
        o = m;
        sp = np_; sq = nq_; so = no_;
    }
}

__global__ __launch_bounds__(192) void wkv_pass3(
    const bf* __restrict__ k, const bf* __restrict__ v, const bf* __restrict__ sr,
    const float* __restrict__ sd, const float* __restrict__ sf,
    const float* __restrict__ iP, const float* __restrict__ iQ,
    const float* __restrict__ iO, bf* __restrict__ z)
{
    const int c2 = threadIdx.x % 96, sub = threadIdx.x / 96;
    const int b = blockIdx.y, ch = blockIdx.x * 2 + sub;
    const int c0 = c2 * 2;
    const float w0 = sd[c0] * Tinv, w1 = sd[c0 + 1] * Tinv;
    const float u0 = sf[c0] * Tinv, u1 = sf[c0 + 1] * Tinv;
    size_t si = ((size_t)b * NS + ch) * cC + c0;
    float2 pp = *reinterpret_cast<const float2*>(iP + si);
    float2 qq = *reinterpret_cast<const float2*>(iQ + si);
    float2 oo = *reinterpret_cast<const float2*>(iO + si);
    float p0 = pp.x, q0 = qq.x, o0 = oo.x;
    float p1 = pp.y, q1 = qq.y, o1 = oo.y;
    size_t base = ((size_t)b * cT + (size_t)ch * CH) * cC + c0;
    unsigned kwc = *reinterpret_cast<const unsigned*>(k + base);
    unsigned vwc = *reinterpret_cast<const unsigned*>(v + base);
    unsigned rwc = *reinterpret_cast<const unsigned*>(sr + base);
    for (int s = 0; s < CH; ++s) {
        unsigned kwn = 0, vwn = 0, rwn = 0;
        if (s + 1 < CH) {
            size_t nx = base + (size_t)(s + 1) * cC;
            kwn = *reinterpret_cast<const unsigned*>(k + nx);
            vwn = *reinterpret_cast<const unsigned*>(v + nx);
            rwn = *reinterpret_cast<const unsigned*>(sr + nx);
        }
        float kt0 = bflo(kwc), kt1 = bfhi(kwc);
        float vt0 = bflo(vwc), vt1 = bfhi(vwc);
        float rt0 = bflo(rwc), rt1 = bfhi(rwc);

        float no0 = fmaxf(o0, u0 + kt0);
        float Ae0 = __expf(o0 - no0), Be0 = __expf(u0 + kt0 - no0);
        float y0 = (Ae0 * p0 + Be0 * vt0) / (Ae0 * q0 + Be0);
        float no1 = fmaxf(o1, u1 + kt1);
        float Ae1 = __expf(o1 - no1), Be1 = __expf(u1 + kt1 - no1);
        float y1 = (Ae1 * p1 + Be1 * vt1) / (Ae1 * q1 + Be1);

        bf z0 = __float2bfloat16(rt0 * y0);
        bf z1 = __float2bfloat16(rt1 * y1);
        unsigned zp = (unsigned)*reinterpret_cast<unsigned short*>(&z0)
                    | ((unsigned)*reinterpret_cast<unsigned short*>(&z1) << 16);
        *reinterpret_cast<unsigned*>(z + base + (size_t)s * cC) = zp;

        float m0 = fmaxf(w0 + o0, kt0);
        float A0 = __expf(w0 + o0 - m0), B0 = __expf(kt0 - m0);
        p0 = A0 * p0 + B0 * vt0; q0 = A0 * q0 + B0; o0 = m0;
        float m1 = fmaxf(w1 + o1, kt1);
        float A1 = __expf(w1 + o1 - m1), B1 = __expf(kt1 - m1);
        p1 = A1 * p1 + B1 * vt1; q1 = A1 * q1 + B1; o1 = m1;
        kwc = kwn; vwc = vwn; rwc = rwn;
    }
}

extern "C" void kernel_launch(void* const* d_in, const int* in_sizes, int n_in,
                              void* d_out, int out_size, void* d_ws, size_t ws_size,
                              hipStream_t stream)
{
    const float* x  = (const float*)d_in[0];
    const float* Wk = (const float*)d_in[1];
    const float* Wv = (const float*)d_in[2];
    const float* Wr = (const float*)d_in[3];
    const float* Wo = (const float*)d_in[4];
    const float* sd = (const float*)d_in[5];
    const float* sf = (const float*)d_in[6];
    float* out = (float*)d_out;

    const size_t nEl = (size_t)cM * cC;          // 28,311,552 elements
    // d_out (f32, 113.2MB) holds k and sr (bf16, 2x56.6MB) until final gemm.
    bf* kbuf  = (bf*)d_out;
    bf* srbuf = (bf*)d_out + nEl;
    char* ws = (char*)d_ws;
    bf* vbuf = (bf*)ws;                           // 56.6MB
    bf* zbuf = (bf*)(ws + 2 * nEl);               // 56.6MB
    const size_t stN = (size_t)cB * NS * cC;      // 589,824 floats each
    float* stP = (float*)(ws + 4 * nEl);          // 3 x 2.36MB (in-place prefix)
    float* stQ = stP + stN;
    float* stO = stQ + stN;
    bf* wbf = (bf*)(stO + stN);                   // [Wk;Wv;Wr;Wo] bf16, 768x192

    convw_k<<<dim3(72), dim3(256), 0, stream>>>(Wk, Wv, Wr, Wo, wbf);
    gemm_k<0><<<dim3(cM / 128), dim3(512), 0, stream>>>(x, wbf, kbuf, vbuf, srbuf);
    wkv_pass1<<<dim3(NS / 2, cB), dim3(192), 0, stream>>>(kbuf, vbuf, sd, stP, stQ, stO);
    wkv_pass2<<<dim3(cB), dim3(192), 0, stream>>>(stP, stQ, stO, sd);
    wkv_pass3<<<dim3(NS / 2, cB), dim3(192), 0, stream>>>(
        kbuf, vbuf, srbuf, sd, sf, stP, stQ, stO, zbuf);
    gemm_k<1><<<dim3(cM / 128), dim3(512), 0, stream>>>(
        zbuf, wbf + (size_t)576 * cC, out, nullptr, nullptr);
}

// Round 14
// 236.356 us; speedup vs baseline: 1.5532x; 1.1538x over previous
//
#include <hip/hip_runtime.h>
#include <hip/hip_bf16.h>

typedef __bf16 bf16x8 __attribute__((ext_vector_type(8)));
typedef float f32x4 __attribute__((ext_vector_type(4)));

using bf = __hip_bfloat16;

constexpr int cB = 16, cH = 96, cW = 96, cC = 192;
constexpr int cT = cH * cW;       // 9216
constexpr int cM = cB * cT;       // 147456
constexpr int CH = 48;            // wkv chunk length
constexpr int NS = cT / CH;       // 192 chunks
constexpr float Tinv = 1.0f / 9216.0f;

__device__ __forceinline__ int swz(int row, int bytecol) {
    return row * 384 + (bytecol ^ ((row & 7) << 4));
}
__device__ __forceinline__ float bflo(unsigned u) { return __uint_as_float(u << 16); }
__device__ __forceinline__ float bfhi(unsigned u) { return __uint_as_float(u & 0xffff0000u); }

// ---------------------------------------------------------------------------
// Pre-convert weights f32 -> bf16, concatenated rows: [Wk;Wv;Wr;Wo] (768x192)
// ---------------------------------------------------------------------------
__global__ __launch_bounds__(256) void convw_k(
    const float* __restrict__ Wk, const float* __restrict__ Wv,
    const float* __restrict__ Wr, const float* __restrict__ Wo,
    bf* __restrict__ out)
{
    int i = (blockIdx.x * 256 + threadIdx.x) * 8;
    int mat = i / 36864, off = i % 36864;
    const float* s = mat == 0 ? Wk : (mat == 1 ? Wv : (mat == 2 ? Wr : Wo));
    const float4* sp = reinterpret_cast<const float4*>(s + off);
    float4 a0 = sp[0], a1 = sp[1];
    bf16x8 pk;
    pk[0]=(__bf16)a0.x; pk[1]=(__bf16)a0.y; pk[2]=(__bf16)a0.z; pk[3]=(__bf16)a0.w;
    pk[4]=(__bf16)a1.x; pk[5]=(__bf16)a1.y; pk[6]=(__bf16)a1.z; pk[7]=(__bf16)a1.w;
    *reinterpret_cast<bf16x8*>(reinterpret_cast<__bf16*>(out) + i) = pk;
}

// ---------------------------------------------------------------------------
// CHAMPION (R7-bench, 245us) GEMM — verbatim. Persistent pipelined:
// 256 blocks (1/CU), 512 threads (8 waves, 2m x 4n).
// LDS: A double-buffer 2x(64x384B)=48KB + full B matrix (192x384B)=72KB.
// Per m-step: issue A-loads(t+1) | compute(t) | store(t) | ds_write(t+1) | bar.
// Outputs [m][c]; scalar stores (proven WRITE == ideal 166MB, no
// amplification).
// MODE 0: A = x(f32)+2D shift; 3 mats -> k / v / sigmoid(r) bf16.
// MODE 1: A = z(bf16); 1 mat (Wo) -> out f32.
// ---------------------------------------------------------------------------
template <int MODE>
__global__ __launch_bounds__(512, 2) void gemm_k(
    const void* __restrict__ Ap, const bf* __restrict__ Wb,
    void* __restrict__ O0, void* __restrict__ O1, void* __restrict__ O2)
{
    constexpr int NMAT = (MODE == 0) ? 3 : 1;
    __shared__ char lds[2 * 64 * 384 + 192 * 384];
    const int tid = threadIdx.x, bx = blockIdx.x;
    const int lane = tid & 63, wid = tid >> 6;
    const int wm = wid >> 2, wn = wid & 3;   // 2m x 4n waves: 32 x 48 each
    const int lr = lane & 15, lq = lane >> 4;

    // per-thread staging coords (3 chunks of 8 elems, fixed per thread)
    int rj[3], kbj[3];
#pragma unroll
    for (int j = 0; j < 3; ++j) { int idx = tid + j * 512; rj[j] = idx / 24; kbj[j] = idx % 24; }

    float4 pf[6];    // MODE0: 3 chunks x 2 float4
    int4   pi[3];    // MODE1: 3 chunks x int4

    for (int mat = 0; mat < NMAT; ++mat) {
        // ---- stage B: full 192x192 bf16 matrix, swizzled ----
        {
            const bf* Wt = Wb + (size_t)mat * 192 * cC;
            char* Bb = &lds[0] + 2 * 64 * 384;
            for (int it = 0; it < 9; ++it) {
                int idx = tid + it * 512;
                int r = idx / 24, kb = idx % 24;
                int4 val = *reinterpret_cast<const int4*>(Wt + r * cC + kb * 8);
                *reinterpret_cast<int4*>(Bb + swz(r, kb * 16)) = val;
            }
        }
        // ---- prologue: load + write A(tile bx) into buf0 ----
        if constexpr (MODE == 0) {
            const float* Af = (const float*)Ap;
#pragma unroll
            for (int j = 0; j < 3; ++j) {
                int gm = bx * 64 + rj[j];
                int b = gm / cT, t = gm % cT, h = t / cW, w = t % cW;
                int grp = kbj[j] / 6;
                int hs = h + (grp == 2 ? -1 : (grp == 3 ? 1 : 0));
                int ws2 = w + (grp == 0 ? -1 : (grp == 1 ? 1 : 0));
                pf[2*j] = float4{0,0,0,0}; pf[2*j+1] = float4{0,0,0,0};
                if (hs >= 0 && hs < cH && ws2 >= 0 && ws2 < cW) {
                    const float4* s = reinterpret_cast<const float4*>(
                        Af + ((size_t)b * cT + (size_t)hs * cW + ws2) * cC + kbj[j] * 8);
                    pf[2*j] = s[0]; pf[2*j+1] = s[1];
                }
            }
#pragma unroll
            for (int j = 0; j < 3; ++j) {
                bf16x8 pk;
                pk[0]=(__bf16)pf[2*j].x; pk[1]=(__bf16)pf[2*j].y; pk[2]=(__bf16)pf[2*j].z; pk[3]=(__bf16)pf[2*j].w;
                pk[4]=(__bf16)pf[2*j+1].x; pk[5]=(__bf16)pf[2*j+1].y; pk[6]=(__bf16)pf[2*j+1].z; pk[7]=(__bf16)pf[2*j+1].w;
                *reinterpret_cast<bf16x8*>(&lds[0] + swz(rj[j], kbj[j] * 16)) = pk;
            }
        } else {
            const bf* Az = (const bf*)Ap;
#pragma unroll
            for (int j = 0; j < 3; ++j)
                pi[j] = *reinterpret_cast<const int4*>(Az + (size_t)(bx * 64 + rj[j]) * cC + kbj[j] * 8);
#pragma unroll
            for (int j = 0; j < 3; ++j)
                *reinterpret_cast<int4*>(&lds[0] + swz(rj[j], kbj[j] * 16)) = pi[j];
        }
        __syncthreads();

        for (int i = 0; i < 9; ++i) {
            const int tix = bx + 256 * i;
            // ---- issue A-loads for next tile (overlap with compute) ----
            if (i < 8) {
                const int tn = bx + 256 * (i + 1);
                if constexpr (MODE == 0) {
                    const float* Af = (const float*)Ap;
#pragma unroll
                    for (int j = 0; j < 3; ++j) {
                        int gm = tn * 64 + rj[j];
                        int b = gm / cT, t = gm % cT, h = t / cW, w = t % cW;
                        int grp = kbj[j] / 6;
                        int hs = h + (grp == 2 ? -1 : (grp == 3 ? 1 : 0));
                        int ws2 = w + (grp == 0 ? -1 : (grp == 1 ? 1 : 0));
                        pf[2*j] = float4{0,0,0,0}; pf[2*j+1] = float4{0,0,0,0};
                        if (hs >= 0 && hs < cH && ws2 >= 0 && ws2 < cW) {
                            const float4* s = reinterpret_cast<const float4*>(
                                Af + ((size_t)b * cT + (size_t)hs * cW + ws2) * cC + kbj[j] * 8);
                            pf[2*j] = s[0]; pf[2*j+1] = s[1];
                        }
                    }
                } else {
                    const bf* Az = (const bf*)Ap;
#pragma unroll
                    for (int j = 0; j < 3; ++j)
                        pi[j] = *reinterpret_cast<const int4*>(Az + (size_t)(tn * 64 + rj[j]) * cC + kbj[j] * 8);
                }
            }
            // ---- compute from buf[i&1] + full-B LDS ----
            char* Ab = &lds[0] + (i & 1) * (64 * 384);
            char* Bb = &lds[0] + 2 * 64 * 384;
            f32x4 acc[2][3] = {};
#pragma unroll
            for (int kk = 0; kk < 6; ++kk) {
                const int bc = kk * 64 + lq * 16;
                bf16x8 af[2], bfr[3];
#pragma unroll
                for (int mt = 0; mt < 2; ++mt)
                    af[mt] = *reinterpret_cast<const bf16x8*>(Ab + swz(wm * 32 + mt * 16 + lr, bc));
#pragma unroll
                for (int nt = 0; nt < 3; ++nt)
                    bfr[nt] = *reinterpret_cast<const bf16x8*>(Bb + swz(wn * 48 + nt * 16 + lr, bc));
#pragma unroll
                for (int mt = 0; mt < 2; ++mt)
#pragma unroll
                    for (int nt = 0; nt < 3; ++nt)
                        acc[mt][nt] = __builtin_amdgcn_mfma_f32_16x16x32_bf16(
                            af[mt], bfr[nt], acc[mt][nt], 0, 0, 0);
            }
            // ---- store tile tix, [m][c] layout ----
            if constexpr (MODE == 0) {
                bf* Os = (bf*)(mat == 0 ? O0 : (mat == 1 ? O1 : O2));
#pragma unroll
                for (int mt = 0; mt < 2; ++mt)
#pragma unroll
                    for (int nt = 0; nt < 3; ++nt)
#pragma unroll
                        for (int j = 0; j < 4; ++j) {
                            int row = tix * 64 + wm * 32 + mt * 16 + lq * 4 + j;
                            int col = wn * 48 + nt * 16 + lr;
                            float v = acc[mt][nt][j];
                            if (mat == 2) v = 1.0f / (1.0f + __expf(-v));
                            Os[(size_t)row * cC + col] = __float2bfloat16(v);
                        }
            } else {
                float* Os = (float*)O0;
#pragma unroll
                for (int mt = 0; mt < 2; ++mt)
#pragma unroll
                    for (int nt = 0; nt < 3; ++nt)
#pragma unroll
                        for (int j = 0; j < 4; ++j) {
                            int row = tix * 64 + wm * 32 + mt * 16 + lq * 4 + j;
                            int col = wn * 48 + nt * 16 + lr;
                            Os[(size_t)row * cC + col] = acc[mt][nt][j];
                        }
            }
            // ---- write next A tile into the other buffer ----
            if (i < 8) {
                char* An = &lds[0] + ((i + 1) & 1) * (64 * 384);
                if constexpr (MODE == 0) {
#pragma unroll
                    for (int j = 0; j < 3; ++j) {
                        bf16x8 pk;
                        pk[0]=(__bf16)pf[2*j].x; pk[1]=(__bf16)pf[2*j].y; pk[2]=(__bf16)pf[2*j].z; pk[3]=(__bf16)pf[2*j].w;
                        pk[4]=(__bf16)pf[2*j+1].x; pk[5]=(__bf16)pf[2*j+1].y; pk[6]=(__bf16)pf[2*j+1].z; pk[7]=(__bf16)pf[2*j+1].w;
                        *reinterpret_cast<bf16x8*>(An + swz(rj[j], kbj[j] * 16)) = pk;
                    }
                } else {
#pragma unroll
                    for (int j = 0; j < 3; ++j)
                        *reinterpret_cast<int4*>(An + swz(rj[j], kbj[j] * 16)) = pi[j];
                }
            }
            __syncthreads();
        }
    }
}

// ---------------------------------------------------------------------------
// WKV (R8-proven): chunked scan over [m][c] bf16, 2 channels/thread, CH=48
// (NS=192 chunks), per-step software prefetch, in-place pass2.
// State: true numerator = p*e^o, denom = q*e^o.
// ---------------------------------------------------------------------------
__global__ __launch_bounds__(192) void wkv_pass1(
    const bf* __restrict__ k, const bf* __restrict__ v,
    const float* __restrict__ sd,
    float* __restrict__ stP, float* __restrict__ stQ, float* __restrict__ stO)
{
    const int c2 = threadIdx.x % 96, sub = threadIdx.x / 96;
    const int b = blockIdx.y, ch = blockIdx.x * 2 + sub;
    const int c0 = c2 * 2;
    const float w0 = sd[c0] * Tinv, w1 = sd[c0 + 1] * Tinv;
    size_t base = ((size_t)b * cT + (size_t)ch * CH) * cC + c0;
    float p0 = 0.f, q0 = 0.f, o0 = -1e38f;
    float p1 = 0.f, q1 = 0.f, o1 = -1e38f;
    unsigned kwc = *reinterpret_cast<const unsigned*>(k + base);
    unsigned vwc = *reinterpret_cast<const unsigned*>(v + base);
    for (int s = 0; s < CH; ++s) {
        unsigned kwn = 0, vwn = 0;
        if (s + 1 < CH) {
            kwn = *reinterpret_cast<const unsigned*>(k + base + (size_t)(s + 1) * cC);
            vwn = *reinterpret_cast<const unsigned*>(v + base + (size_t)(s + 1) * cC);
        }
        float kt0 = bflo(kwc), kt1 = bfhi(kwc);
        float vt0 = bflo(vwc), vt1 = bfhi(vwc);
        float no0 = fmaxf(w0 + o0, kt0);
        float A0 = __expf(w0 + o0 - no0), B0 = __expf(kt0 - no0);
        p0 = A0 * p0 + B0 * vt0; q0 = A0 * q0 + B0; o0 = no0;
        float no1 = fmaxf(w1 + o1, kt1);
        float A1 = __expf(w1 + o1 - no1), B1 = __expf(kt1 - no1);
        p1 = A1 * p1 + B1 * vt1; q1 = A1 * q1 + B1; o1 = no1;
        kwc = kwn; vwc = vwn;
    }
    size_t si = ((size_t)b * NS + ch) * cC + c0;
    *reinterpret_cast<float2*>(stP + si) = make_float2(p0, p1);
    *reinterpret_cast<float2*>(stQ + si) = make_float2(q0, q1);
    *reinterpret_cast<float2*>(stO + si) = make_float2(o0, o1);
}

// In-place exclusive prefix over chunk states.
__global__ __launch_bounds__(192) void wkv_pass2(
    float* __restrict__ stP, float* __restrict__ stQ, float* __restrict__ stO,
    const float* __restrict__ sd)
{
    const int c = threadIdx.x, b = blockIdx.x;
    const float w = sd[c] * Tinv;
    const float Lw = w * (float)CH;
    float p = 0.f, q = 0.f, o = -1e38f;
    size_t si = (size_t)b * NS * cC + c;
    float sp = stP[si], sq = stQ[si], so = stO[si];
    for (int ch = 0; ch < NS; ++ch) {
        float np_ = 0.f, nq_ = 0.f, no_ = -1e38f;
        if (ch + 1 < NS) {
            size_t sj = si + (size_t)(ch + 1) * cC;
            np_ = stP[sj]; nq_ = stQ[sj]; no_ = stO[sj];
        }
        size_t sc = si + (size_t)ch * cC;
        stP[sc] = p; stQ[sc] = q; stO[sc] = o;
        float po = o + Lw;
        float m = fmaxf(po, so);
        float e1 = __expf(po - m), e2 = __expf(so - m);
        p = e1 * p + e2 * sp;
        q = e1 * q + e2 * sq;
        o = m;
        sp = np_; sq = nq_; so = no_;
    }
}

__global__ __launch_bounds__(192) void wkv_pass3(
    const bf* __restrict__ k, const bf* __restrict__ v, const bf* __restrict__ sr,
    const float* __restrict__ sd, const float* __restrict__ sf,
    const float* __restrict__ iP, const float* __restrict__ iQ,
    const float* __restrict__ iO, bf* __restrict__ z)
{
    const int c2 = threadIdx.x % 96, sub = threadIdx.x / 96;
    const int b = blockIdx.y, ch = blockIdx.x * 2 + sub;
    const int c0 = c2 * 2;
    const float w0 = sd[c0] * Tinv, w1 = sd[c0 + 1] * Tinv;
    const float u0 = sf[c0] * Tinv, u1 = sf[c0 + 1] * Tinv;
    size_t si = ((size_t)b * NS + ch) * cC + c0;
    float2 pp = *reinterpret_cast<const float2*>(iP + si);
    float2 qq = *reinterpret_cast<const float2*>(iQ + si);
    float2 oo = *reinterpret_cast<const float2*>(iO + si);
    float p0 = pp.x, q0 = qq.x, o0 = oo.x;
    float p1 = pp.y, q1 = qq.y, o1 = oo.y;
    size_t base = ((size_t)b * cT + (size_t)ch * CH) * cC + c0;
    unsigned kwc = *reinterpret_cast<const unsigned*>(k + base);
    unsigned vwc = *reinterpret_cast<const unsigned*>(v + base);
    unsigned rwc = *reinterpret_cast<const unsigned*>(sr + base);
    for (int s = 0; s < CH; ++s) {
        unsigned kwn = 0, vwn = 0, rwn = 0;
        if (s + 1 < CH) {
            size_t nx = base + (size_t)(s + 1) * cC;
            kwn = *reinterpret_cast<const unsigned*>(k + nx);
            vwn = *reinterpret_cast<const unsigned*>(v + nx);
            rwn = *reinterpret_cast<const unsigned*>(sr + nx);
        }
        float kt0 = bflo(kwc), kt1 = bfhi(kwc);
        float vt0 = bflo(vwc), vt1 = bfhi(vwc);
        float rt0 = bflo(rwc), rt1 = bfhi(rwc);

        float no0 = fmaxf(o0, u0 + kt0);
        float Ae0 = __expf(o0 - no0), Be0 = __expf(u0 + kt0 - no0);
        float y0 = (Ae0 * p0 + Be0 * vt0) / (Ae0 * q0 + Be0);
        float no1 = fmaxf(o1, u1 + kt1);
        float Ae1 = __expf(o1 - no1), Be1 = __expf(u1 + kt1 - no1);
        float y1 = (Ae1 * p1 + Be1 * vt1) / (Ae1 * q1 + Be1);

        bf z0 = __float2bfloat16(rt0 * y0);
        bf z1 = __float2bfloat16(rt1 * y1);
        unsigned zp = (unsigned)*reinterpret_cast<unsigned short*>(&z0)
                    | ((unsigned)*reinterpret_cast<unsigned short*>(&z1) << 16);
        *reinterpret_cast<unsigned*>(z + base + (size_t)s * cC) = zp;

        float m0 = fmaxf(w0 + o0, kt0);
        float A0 = __expf(w0 + o0 - m0), B0 = __expf(kt0 - m0);
        p0 = A0 * p0 + B0 * vt0; q0 = A0 * q0 + B0; o0 = m0;
        float m1 = fmaxf(w1 + o1, kt1);
        float A1 = __expf(w1 + o1 - m1), B1 = __expf(kt1 - m1);
        p1 = A1 * p1 + B1 * vt1; q1 = A1 * q1 + B1; o1 = m1;
        kwc = kwn; vwc = vwn; rwc = rwn;
    }
}

extern "C" void kernel_launch(void* const* d_in, const int* in_sizes, int n_in,
                              void* d_out, int out_size, void* d_ws, size_t ws_size,
                              hipStream_t stream)
{
    const float* x  = (const float*)d_in[0];
    const float* Wk = (const float*)d_in[1];
    const float* Wv = (const float*)d_in[2];
    const float* Wr = (const float*)d_in[3];
    const float* Wo = (const float*)d_in[4];
    const float* sd = (const float*)d_in[5];
    const float* sf = (const float*)d_in[6];
    float* out = (float*)d_out;

    const size_t nEl = (size_t)cM * cC;          // 28,311,552 elements
    // d_out (f32, 113.2MB) holds k and sr (bf16, 2x56.6MB) until final gemm.
    bf* kbuf  = (bf*)d_out;
    bf* srbuf = (bf*)d_out + nEl;
    char* ws = (char*)d_ws;
    bf* vbuf = (bf*)ws;                           // 56.6MB
    bf* zbuf = (bf*)(ws + 2 * nEl);               // 56.6MB
    const size_t stN = (size_t)cB * NS * cC;      // 589,824 floats each
    float* stP = (float*)(ws + 4 * nEl);          // 3 x 2.36MB (in-place prefix)
    float* stQ = stP + stN;
    float* stO = stQ + stN;
    bf* wbf = (bf*)(stO + stN);                   // [Wk;Wv;Wr;Wo] bf16, 768x192

    convw_k<<<dim3(72), dim3(256), 0, stream>>>(Wk, Wv, Wr, Wo, wbf);
    gemm_k<0><<<dim3(256), dim3(512), 0, stream>>>(x, wbf, kbuf, vbuf, srbuf);
    wkv_pass1<<<dim3(NS / 2, cB), dim3(192), 0, stream>>>(kbuf, vbuf, sd, stP, stQ, stO);
    wkv_pass2<<<dim3(cB), dim3(192), 0, stream>>>(stP, stQ, stO, sd);
    wkv_pass3<<<dim3(NS / 2, cB), dim3(192), 0, stream>>>(
        kbuf, vbuf, srbuf, sd, sf, stP, stQ, stO, zbuf);
    gemm_k<1><<<dim3(256), dim3(512), 0, stream>>>(
        zbuf, wbf + (size_t)576 * cC, out, nullptr, nullptr);
}